// Round 2
// baseline (261.153 us; speedup 1.0000x reference)
//
#include <hip/hip_runtime.h>

#define S_LEN   2048
#define BATCH   32
#define NF      1024
#define CTX     20
#define KW      21            // taps
#define T_OUT   128           // output t-steps per tile
#define F_TILE  32            // features per block
#define NROWS_REAL (T_OUT + CTX)   // 148 rows actually read
#define NROWS_PAD  160             // 20 chunks x 8 rows; rows 148..159 junk (never read)
#define BUF_FLOATS (NROWS_PAD * F_TILE)  // 5120 floats = 20480 B per buffer
#define R_PER_T 4
#define T_WIN   (R_PER_T + CTX)    // 24 sliding-window rows per thread

#define WAITV(n) asm volatile("s_waitcnt vmcnt(" #n ")" ::: "memory")

// Stage one t-tile (160 rows x 128B) into LDS buffer via direct global->LDS DMA.
// LDS dest is linear (chunk*1024B + lane*16B); the XOR swizzle slot = f4 ^ (row&7)
// is applied by pre-swizzling the per-lane GLOBAL source address.
__device__ __forceinline__ void stage_tile(const float* __restrict__ x,
                                           float* buf, int t0_s, int b,
                                           int f0, int wv_id, int rsub, int f4src) {
    #pragma unroll
    for (int j = 0; j < 5; ++j) {
        int chunk = j * 4 + wv_id;        // 0..19, wave-uniform
        int row   = chunk * 8 + rsub;     // 0..159, per-lane
        int t     = t0_s + row;
        t = (t < S_LEN) ? t : (S_LEN - 1);   // clamp: pad rows re-read (L1/L2 hot)
        const float* src = x + ((size_t)t * BATCH + b) * NF + f0 + (f4src << 2);
        __builtin_amdgcn_global_load_lds(
            (const __attribute__((address_space(1))) void*)src,
            (__attribute__((address_space(3))) void*)(buf + chunk * 256),
            16, 0, 0);
    }
}

__global__ __launch_bounds__(256, 4)
void lookahead_dwconv_kernel(const float* __restrict__ x,
                             const float* __restrict__ w,
                             float* __restrict__ out) {
    __shared__ float xlds[2][BUF_FLOATS];   // 40960 B -> 4 blocks/CU

    const int tid    = threadIdx.x;
    const int f_tile = blockIdx.x;   // 0..31
    const int b      = blockIdx.y;   // 0..31
    const int f0     = f_tile * F_TILE;

    const int wv_id = tid >> 6;          // wave id 0..3
    const int lane  = tid & 63;
    const int rsub  = (lane >> 3) & 7;   // row within 8-row chunk
    const int f4src = (lane & 7) ^ rsub; // pre-swizzled source f4 slot

    // compute-phase mapping
    const int f4    = tid & 7;           // float4 slot of features
    const int tg    = tid >> 3;          // 0..31
    const int tbase = tg * R_PER_T;      // 0..124

    // ---- weights -> registers, once per block (L2-hot, amortized 16 tiles) ----
    float wv[4][KW];
    {
        const float* wp = w + (size_t)(f0 + f4 * 4) * KW;
        #pragma unroll
        for (int c = 0; c < 4; ++c)
            #pragma unroll
            for (int k = 0; k < KW; ++k)
                wv[c][k] = wp[c * KW + k];
    }

    // ---- prologue: stage tile 0 into buf 0 ----
    stage_tile(x, xlds[0], 0, b, f0, wv_id, rsub, f4src);

    for (int t_tile = 0; t_tile < 16; ++t_tile) {
        const int cur = t_tile & 1;
        const int t0  = t_tile * T_OUT;

        // prefetch next tile into the other buffer (loads stay in flight across barrier)
        if (t_tile < 15)
            stage_tile(x, xlds[cur ^ 1], t0 + T_OUT, b, f0, wv_id, rsub, f4src);

        // counted waits: need THIS tile's 5 loads complete.
        // queue (old->new): [loads(cur):5][stores(prev):4][loads(next):5]
        if (t_tile == 0)       WAITV(5);
        else if (t_tile < 15)  WAITV(9);
        else                   WAITV(4);
        __builtin_amdgcn_s_barrier();

        const float* bp = xlds[cur];

        float4 acc[R_PER_T];
        #pragma unroll
        for (int r = 0; r < R_PER_T; ++r)
            acc[r] = make_float4(0.f, 0.f, 0.f, 0.f);

        // register sliding window over 24 staged rows
        #pragma unroll
        for (int s = 0; s < T_WIN; ++s) {
            const int row = tbase + s;
            float4 xv = *reinterpret_cast<const float4*>(
                &bp[row * F_TILE + ((f4 ^ (row & 7)) << 2)]);  // swizzled read
            if (t0 + row >= S_LEN) xv = make_float4(0.f, 0.f, 0.f, 0.f);
            #pragma unroll
            for (int r = 0; r < R_PER_T; ++r) {
                const int k = s - r;
                if (k >= 0 && k < KW) {
                    acc[r].x = fmaf(xv.x, wv[0][k], acc[r].x);
                    acc[r].y = fmaf(xv.y, wv[1][k], acc[r].y);
                    acc[r].z = fmaf(xv.z, wv[2][k], acc[r].z);
                    acc[r].w = fmaf(xv.w, wv[3][k], acc[r].w);
                }
            }
        }

        // release the buffer BEFORE stores: all ds_reads consumed by FMAs above
        __builtin_amdgcn_s_barrier();

        size_t obase = ((size_t)(t0 + tbase) * BATCH + b) * NF + f0 + (f4 << 2);
        #pragma unroll
        for (int r = 0; r < R_PER_T; ++r)
            *reinterpret_cast<float4*>(&out[obase + (size_t)r * BATCH * NF]) = acc[r];
    }
}

extern "C" void kernel_launch(void* const* d_in, const int* in_sizes, int n_in,
                              void* d_out, int out_size, void* d_ws, size_t ws_size,
                              hipStream_t stream) {
    const float* x = (const float*)d_in[0];
    const float* w = (const float*)d_in[1];
    float* out     = (float*)d_out;

    dim3 grid(NF / F_TILE, BATCH);   // (32, 32) = 1024 blocks, 4/CU resident
    dim3 block(256);
    lookahead_dwconv_kernel<<<grid, block, 0, stream>>>(x, w, out);
}

// Round 3
// 123.420 us; speedup vs baseline: 2.1160x; 2.1160x over previous
//
#include <hip/hip_runtime.h>

#define S_LEN   2048
#define BATCH   32
#define NF      1024
#define CTX     20
#define KW      21            // taps
#define T_OUT   128           // output t-steps per tile
#define F_TILE  32            // features per block
#define NCHUNK  20            // 8-row DMA chunks staged (160 rows; 148 used)
#define BUF_FLOATS (NCHUNK * 8 * F_TILE)  // 5120 floats = 20480 B per buffer
#define R_PER_T 4
#define T_WIN   (R_PER_T + CTX)    // 24 sliding-window rows per thread

#define WAITV(n) asm volatile("s_waitcnt vmcnt(" #n ")" ::: "memory")

// Stage one t-tile (160 rows x 128B) into LDS via direct global->LDS DMA.
// LDS dest linear (chunk*1024B + lane*16B); XOR swizzle slot = f4 ^ (row&7)
// applied by pre-swizzling the per-lane GLOBAL source address (rule 21).
__device__ __forceinline__ void stage_tile(const float* __restrict__ x,
                                           float* buf, int t0_s, int b,
                                           int f0, int wv_id, int rsub, int f4src) {
    #pragma unroll
    for (int j = 0; j < 5; ++j) {
        int chunk = j * 4 + wv_id;        // 0..19, wave-uniform
        int row   = chunk * 8 + rsub;     // 0..159, per-lane
        int t     = t0_s + row;
        t = (t < S_LEN) ? t : (S_LEN - 1);   // clamp: junk rows stay in-bounds
        const float* src = x + ((size_t)t * BATCH + b) * NF + f0 + (f4src << 2);
        __builtin_amdgcn_global_load_lds(
            (const __attribute__((address_space(1))) void*)src,
            (__attribute__((address_space(3))) void*)(buf + chunk * 256),
            16, 0, 0);
    }
}

__global__ __launch_bounds__(256)   // NO min-waves arg: R2's ",4" capped VGPR=64 -> spill
void lookahead_dwconv_kernel(const float* __restrict__ x,
                             const float* __restrict__ w,
                             float* __restrict__ out) {
    __shared__ float xlds[2][BUF_FLOATS];   // 40960 B -> 4 blocks/CU (LDS-capped)

    const int tid    = threadIdx.x;
    const int f_tile = blockIdx.x;   // 0..31
    const int b      = blockIdx.y;   // 0..31
    const int f0     = f_tile * F_TILE;

    const int wv_id = tid >> 6;          // wave id 0..3
    const int lane  = tid & 63;
    const int rsub  = (lane >> 3) & 7;   // row within 8-row chunk
    const int f4src = (lane & 7) ^ rsub; // pre-swizzled source f4 slot

    // compute-phase mapping
    const int f4    = tid & 7;           // float4 slot of features
    const int tg    = tid >> 3;          // 0..31
    const int tbase = tg * R_PER_T;      // 0..124

    // ---- weights -> registers, once per block (L2-hot; ~110 live VGPRs total) ----
    float wv[4][KW];
    {
        const float* wp = w + (size_t)(f0 + f4 * 4) * KW;
        #pragma unroll
        for (int c = 0; c < 4; ++c)
            #pragma unroll
            for (int k = 0; k < KW; ++k)
                wv[c][k] = wp[c * KW + k];
    }

    // ---- prologue: stage tile 0 into buf 0 ----
    stage_tile(x, xlds[0], 0, b, f0, wv_id, rsub, f4src);

    #pragma unroll 1
    for (int t_tile = 0; t_tile < 16; ++t_tile) {
        const int cur = t_tile & 1;
        const int t0  = t_tile * T_OUT;

        // prefetch next tile into the other buffer (stays in flight across barrier)
        if (t_tile < 15)
            stage_tile(x, xlds[cur ^ 1], t0 + T_OUT, b, f0, wv_id, rsub, f4src);

        // counted waits: need THIS tile's 5 loads complete.
        // queue (old->new): [loads(cur):5][stores(prev):4][loads(next):5]
        if (t_tile == 0)       WAITV(5);
        else if (t_tile < 15)  WAITV(9);
        else                   WAITV(4);
        __builtin_amdgcn_s_barrier();

        const float* bp = xlds[cur];

        float4 acc[R_PER_T];
        #pragma unroll
        for (int r = 0; r < R_PER_T; ++r)
            acc[r] = make_float4(0.f, 0.f, 0.f, 0.f);

        if (t_tile < 15) {
            // fast path: no boundary handling (rows t0..t0+147 all < S_LEN)
            #pragma unroll
            for (int s = 0; s < T_WIN; ++s) {
                const int row = tbase + s;
                float4 xv = *reinterpret_cast<const float4*>(
                    &bp[row * F_TILE + ((f4 ^ (row & 7)) << 2)]);  // swizzled read
                #pragma unroll
                for (int r = 0; r < R_PER_T; ++r) {
                    const int k = s - r;
                    if (k >= 0 && k < KW) {
                        acc[r].x = fmaf(xv.x, wv[0][k], acc[r].x);
                        acc[r].y = fmaf(xv.y, wv[1][k], acc[r].y);
                        acc[r].z = fmaf(xv.z, wv[2][k], acc[r].z);
                        acc[r].w = fmaf(xv.w, wv[3][k], acc[r].w);
                    }
                }
            }
        } else {
            // boundary tile: zero rows past S_LEN
            #pragma unroll
            for (int s = 0; s < T_WIN; ++s) {
                const int row = tbase + s;
                float4 xv = *reinterpret_cast<const float4*>(
                    &bp[row * F_TILE + ((f4 ^ (row & 7)) << 2)]);
                if (t0 + row >= S_LEN) xv = make_float4(0.f, 0.f, 0.f, 0.f);
                #pragma unroll
                for (int r = 0; r < R_PER_T; ++r) {
                    const int k = s - r;
                    if (k >= 0 && k < KW) {
                        acc[r].x = fmaf(xv.x, wv[0][k], acc[r].x);
                        acc[r].y = fmaf(xv.y, wv[1][k], acc[r].y);
                        acc[r].z = fmaf(xv.z, wv[2][k], acc[r].z);
                        acc[r].w = fmaf(xv.w, wv[3][k], acc[r].w);
                    }
                }
            }
        }

        // release the buffer BEFORE stores: all ds_reads consumed above
        __builtin_amdgcn_s_barrier();

        size_t obase = ((size_t)(t0 + tbase) * BATCH + b) * NF + f0 + (f4 << 2);
        #pragma unroll
        for (int r = 0; r < R_PER_T; ++r)
            *reinterpret_cast<float4*>(&out[obase + (size_t)r * BATCH * NF]) = acc[r];
    }
}

extern "C" void kernel_launch(void* const* d_in, const int* in_sizes, int n_in,
                              void* d_out, int out_size, void* d_ws, size_t ws_size,
                              hipStream_t stream) {
    const float* x = (const float*)d_in[0];
    const float* w = (const float*)d_in[1];
    float* out     = (float*)d_out;

    dim3 grid(NF / F_TILE, BATCH);   // (32, 32) = 1024 blocks, 4/CU resident
    dim3 block(256);
    lookahead_dwconv_kernel<<<grid, block, 0, stream>>>(x, w, out);
}

// Round 5
// 91.231 us; speedup vs baseline: 2.8625x; 1.3528x over previous
//
#include <hip/hip_runtime.h>

#define S_LEN   2048
#define BATCH   32
#define NF      1024
#define CTX     20
#define KW      21            // taps
#define T_OUT   256           // output t-steps per tile
#define F_TILE  32            // features per block
#define NCHUNK  36            // 8-row DMA chunks staged (288 rows; 276 used)
#define BUF_FLOATS (NCHUNK * 8 * F_TILE)  // 9216 floats = 36864 B per buffer
#define R_PER_T 8
#define T_WIN   (R_PER_T + CTX)    // 28 sliding-window rows per thread
#define N_TILES (S_LEN / T_OUT)    // 8

#define WAITV(n) asm volatile("s_waitcnt vmcnt(" #n ")" ::: "memory")

typedef float f32x4_t __attribute__((ext_vector_type(4)));  // native vec for nontemporal

// Stage one t-tile (288 rows x 128B) into LDS via direct global->LDS DMA.
// Linear layout both sides: chunk c, lane l -> LDS offset c*1024 + l*16,
// global row = c*8 + (l>>3), f4 = l&7. No swizzle: with R_PER_T=8 the
// compute-read row is wave-uniform per window step -> broadcast-free linear.
__device__ __forceinline__ void stage_tile(const float* __restrict__ x,
                                           float* buf, int t0_s, int b,
                                           int f0, int wv_id, int rsub, int f4l) {
    #pragma unroll
    for (int j = 0; j < 9; ++j) {
        int chunk = j * 4 + wv_id;        // 0..35, wave-uniform
        int row   = chunk * 8 + rsub;     // 0..287, per-lane
        int t     = t0_s + row;
        t = (t < S_LEN) ? t : (S_LEN - 1);   // clamp: junk rows stay in-bounds
        const float* src = x + ((size_t)t * BATCH + b) * NF + f0 + (f4l << 2);
        __builtin_amdgcn_global_load_lds(
            (const __attribute__((address_space(1))) void*)src,
            (__attribute__((address_space(3))) void*)(buf + chunk * 256),
            16, 0, 0);
    }
}

__global__ __launch_bounds__(256)   // no min-waves arg (R2 lesson: ",4" forced spill)
void lookahead_dwconv_kernel(const float* __restrict__ x,
                             const float* __restrict__ w,
                             float* __restrict__ out) {
    __shared__ float xlds[2][BUF_FLOATS];   // 73728 B -> 2 blocks/CU

    const int tid    = threadIdx.x;
    const int f_tile = blockIdx.x;   // 0..31
    const int b      = blockIdx.y;   // 0..31
    const int f0     = f_tile * F_TILE;

    const int wv_id = tid >> 6;          // wave id 0..3
    const int lane  = tid & 63;
    const int rsub  = lane >> 3;         // row within 8-row chunk (0..7)
    const int f4l   = lane & 7;          // f4 slot for staging

    // compute-phase mapping
    const int f4    = tid & 7;           // float4 slot of features
    const int tg    = tid >> 3;          // 0..31
    const int tbase = tg * R_PER_T;      // 0..248

    // ---- weights -> registers, once per block (L2-hot, amortized 8 tiles) ----
    float wv[4][KW];
    {
        const float* wp = w + (size_t)(f0 + f4 * 4) * KW;
        #pragma unroll
        for (int c = 0; c < 4; ++c)
            #pragma unroll
            for (int k = 0; k < KW; ++k)
                wv[c][k] = wp[c * KW + k];
    }

    // ---- prologue: stage tile 0 into buf 0 ----
    stage_tile(x, xlds[0], 0, b, f0, wv_id, rsub, f4l);

    #pragma unroll 1
    for (int t_tile = 0; t_tile < N_TILES; ++t_tile) {
        const int cur = t_tile & 1;
        const int t0  = t_tile * T_OUT;

        // prefetch next tile into the other buffer (stays in flight across barrier)
        if (t_tile < N_TILES - 1)
            stage_tile(x, xlds[cur ^ 1], t0 + T_OUT, b, f0, wv_id, rsub, f4l);

        // counted waits, queue oldest->newest:
        //   t==0:    [loads(0):9][loads(1):9]                  -> vmcnt(9)
        //   middle:  [loads(t):9][stores(t-1):8][loads(t+1):9] -> vmcnt(17)
        //   t==N-1:  [loads(t):9][stores(t-1):8]               -> vmcnt(8)
        if (t_tile == 0)                 WAITV(9);
        else if (t_tile < N_TILES - 1)   WAITV(17);
        else                             WAITV(8);
        __builtin_amdgcn_s_barrier();

        const float* bp = xlds[cur];

        float4 acc[R_PER_T];
        #pragma unroll
        for (int r = 0; r < R_PER_T; ++r)
            acc[r] = make_float4(0.f, 0.f, 0.f, 0.f);

        if (t_tile < N_TILES - 1) {
            // fast path: all window rows < S_LEN
            #pragma unroll
            for (int s = 0; s < T_WIN; ++s) {
                const int row = tbase + s;
                float4 xv = *reinterpret_cast<const float4*>(
                    &bp[row * F_TILE + (f4 << 2)]);   // linear: base + s*128B imm
                #pragma unroll
                for (int r = 0; r < R_PER_T; ++r) {
                    const int k = s - r;
                    if (k >= 0 && k < KW) {
                        acc[r].x = fmaf(xv.x, wv[0][k], acc[r].x);
                        acc[r].y = fmaf(xv.y, wv[1][k], acc[r].y);
                        acc[r].z = fmaf(xv.z, wv[2][k], acc[r].z);
                        acc[r].w = fmaf(xv.w, wv[3][k], acc[r].w);
                    }
                }
            }
        } else {
            // boundary tile: zero rows past S_LEN
            #pragma unroll
            for (int s = 0; s < T_WIN; ++s) {
                const int row = tbase + s;
                float4 xv = *reinterpret_cast<const float4*>(
                    &bp[row * F_TILE + (f4 << 2)]);
                if (t0 + row >= S_LEN) xv = make_float4(0.f, 0.f, 0.f, 0.f);
                #pragma unroll
                for (int r = 0; r < R_PER_T; ++r) {
                    const int k = s - r;
                    if (k >= 0 && k < KW) {
                        acc[r].x = fmaf(xv.x, wv[0][k], acc[r].x);
                        acc[r].y = fmaf(xv.y, wv[1][k], acc[r].y);
                        acc[r].z = fmaf(xv.z, wv[2][k], acc[r].z);
                        acc[r].w = fmaf(xv.w, wv[3][k], acc[r].w);
                    }
                }
            }
        }

        // release the buffer BEFORE stores: all ds_reads consumed above
        __builtin_amdgcn_s_barrier();

        size_t obase = ((size_t)(t0 + tbase) * BATCH + b) * NF + f0 + (f4 << 2);
        #pragma unroll
        for (int r = 0; r < R_PER_T; ++r) {
            f32x4_t v = { acc[r].x, acc[r].y, acc[r].z, acc[r].w };
            __builtin_nontemporal_store(v,
                reinterpret_cast<f32x4_t*>(&out[obase + (size_t)r * BATCH * NF]));
        }
    }
}

extern "C" void kernel_launch(void* const* d_in, const int* in_sizes, int n_in,
                              void* d_out, int out_size, void* d_ws, size_t ws_size,
                              hipStream_t stream) {
    const float* x = (const float*)d_in[0];
    const float* w = (const float*)d_in[1];
    float* out     = (float*)d_out;

    dim3 grid(NF / F_TILE, BATCH);   // (32, 32) = 1024 blocks
    dim3 block(256);
    lookahead_dwconv_kernel<<<grid, block, 0, stream>>>(x, w, out);
}

// Round 7
// 88.349 us; speedup vs baseline: 2.9559x; 1.0326x over previous
//
#include <hip/hip_runtime.h>

#define S_LEN   2048
#define BATCH   32
#define NF      1024
#define CTX     20
#define KW      21            // taps
#define T_OUT   128           // output t-steps per tile
#define F_TILE  32            // features per block
#define NCHUNK  20            // 8-row DMA chunks staged (160 rows; 148 used)
#define BUF_FLOATS (NCHUNK * 8 * F_TILE)  // 5120 floats = 20480 B per buffer
#define R_PER_T 4
#define T_WIN   (R_PER_T + CTX)    // 24 sliding-window rows per thread
#define N_TILES (S_LEN / T_OUT)    // 16

#define WAITV(n) asm volatile("s_waitcnt vmcnt(" #n ")" ::: "memory")

typedef float f32x4_t __attribute__((ext_vector_type(4)));

// Stage one t-tile (160 rows x 128B) into LDS via direct global->LDS DMA.
// LDS dest linear: chunk*1024B + lane*16B -> LDS[row][p], row=chunk*8+(l>>3), p=l&7.
// Swizzle (rule 21, both-sides): LDS[row][p] holds f4 = p ^ ((row>>2)&7), achieved
// by pre-swizzling the per-lane GLOBAL source address. Reader uses p = f4 ^ ((row>>2)&7):
// same-f4 lanes (rows differing by 4) then hit 8 distinct slots -> conflict-free.
__device__ __forceinline__ void stage_tile(const float* __restrict__ x,
                                           float* buf, int t0_s, int b,
                                           int f0, int wv_id, int rsub, int p) {
    #pragma unroll
    for (int j = 0; j < 5; ++j) {
        int chunk = j * 4 + wv_id;        // 0..19, wave-uniform
        int row   = chunk * 8 + rsub;     // 0..159, per-lane
        int f4src = p ^ ((row >> 2) & 7); // pre-swizzled source slot
        int t     = t0_s + row;
        t = (t < S_LEN) ? t : (S_LEN - 1);   // clamp: junk rows stay in-bounds
        const float* src = x + ((size_t)t * BATCH + b) * NF + f0 + (f4src << 2);
        __builtin_amdgcn_global_load_lds(
            (const __attribute__((address_space(1))) void*)src,
            (__attribute__((address_space(3))) void*)(buf + chunk * 256),
            16, 0, 0);
    }
}

__global__ __launch_bounds__(256)   // no min-waves arg (R2 lesson: ",4" forced spill)
void lookahead_dwconv_kernel(const float* __restrict__ x,
                             const float* __restrict__ w,
                             float* __restrict__ out) {
    __shared__ float xlds[2][BUF_FLOATS];   // 40960 B -> exactly 4 blocks/CU

    const int tid    = threadIdx.x;
    const int f_tile = blockIdx.x;   // 0..31
    const int b      = blockIdx.y;   // 0..31
    const int f0     = f_tile * F_TILE;

    const int wv_id = tid >> 6;          // wave id 0..3
    const int lane  = tid & 63;
    const int rsub  = lane >> 3;         // row within 8-row chunk (0..7)
    const int pl    = lane & 7;          // LDS slot for staging

    // compute-phase mapping
    const int f4    = tid & 7;           // float4 slot of features
    const int tg    = tid >> 3;          // 0..31
    const int tbase = tg * R_PER_T;      // 0..124

    // ---- weights -> registers, once per block (L2-hot, amortized 16 tiles) ----
    float wv[4][KW];
    {
        const float* wp = w + (size_t)(f0 + f4 * 4) * KW;
        #pragma unroll
        for (int c = 0; c < 4; ++c)
            #pragma unroll
            for (int k = 0; k < KW; ++k)
                wv[c][k] = wp[c * KW + k];
    }

    // ---- prologue: stage tile 0 into buf 0 ----
    stage_tile(x, xlds[0], 0, b, f0, wv_id, rsub, pl);

    #pragma unroll 1
    for (int t_tile = 0; t_tile < N_TILES; ++t_tile) {
        const int cur = t_tile & 1;
        const int t0  = t_tile * T_OUT;

        // prefetch next tile into the other buffer (stays in flight across barrier)
        if (t_tile < N_TILES - 1)
            stage_tile(x, xlds[cur ^ 1], t0 + T_OUT, b, f0, wv_id, rsub, pl);

        // counted waits, per-wave queue oldest->newest (5 loads/wave, 4 stores/wave):
        //   t==0:    [loads(0):5][loads(1):5]                  -> vmcnt(5)
        //   middle:  [loads(t):5][stores(t-1):4][loads(t+1):5] -> vmcnt(9)
        //   t==N-1:  [loads(t):5][stores(t-1):4]               -> vmcnt(4)
        if (t_tile == 0)                 WAITV(5);
        else if (t_tile < N_TILES - 1)   WAITV(9);
        else                             WAITV(4);
        __builtin_amdgcn_s_barrier();

        const float* bp = xlds[cur];

        float4 acc[R_PER_T];
        #pragma unroll
        for (int r = 0; r < R_PER_T; ++r)
            acc[r] = make_float4(0.f, 0.f, 0.f, 0.f);

        if (t_tile < N_TILES - 1) {
            // fast path: all window rows < S_LEN
            #pragma unroll
            for (int s = 0; s < T_WIN; ++s) {
                const int row = tbase + s;
                float4 xv = *reinterpret_cast<const float4*>(
                    &bp[row * F_TILE + ((f4 ^ ((row >> 2) & 7)) << 2)]);
                #pragma unroll
                for (int r = 0; r < R_PER_T; ++r) {
                    const int k = s - r;
                    if (k >= 0 && k < KW) {
                        acc[r].x = fmaf(xv.x, wv[0][k], acc[r].x);
                        acc[r].y = fmaf(xv.y, wv[1][k], acc[r].y);
                        acc[r].z = fmaf(xv.z, wv[2][k], acc[r].z);
                        acc[r].w = fmaf(xv.w, wv[3][k], acc[r].w);
                    }
                }
            }
        } else {
            // boundary tile: zero rows past S_LEN
            #pragma unroll
            for (int s = 0; s < T_WIN; ++s) {
                const int row = tbase + s;
                float4 xv = *reinterpret_cast<const float4*>(
                    &bp[row * F_TILE + ((f4 ^ ((row >> 2) & 7)) << 2)]);
                if (t0 + row >= S_LEN) xv = make_float4(0.f, 0.f, 0.f, 0.f);
                #pragma unroll
                for (int r = 0; r < R_PER_T; ++r) {
                    const int k = s - r;
                    if (k >= 0 && k < KW) {
                        acc[r].x = fmaf(xv.x, wv[0][k], acc[r].x);
                        acc[r].y = fmaf(xv.y, wv[1][k], acc[r].y);
                        acc[r].z = fmaf(xv.z, wv[2][k], acc[r].z);
                        acc[r].w = fmaf(xv.w, wv[3][k], acc[r].w);
                    }
                }
            }
        }

        // release the buffer BEFORE stores: all ds_reads consumed above
        __builtin_amdgcn_s_barrier();

        size_t obase = ((size_t)(t0 + tbase) * BATCH + b) * NF + f0 + (f4 << 2);
        #pragma unroll
        for (int r = 0; r < R_PER_T; ++r) {
            f32x4_t v = { acc[r].x, acc[r].y, acc[r].z, acc[r].w };
            __builtin_nontemporal_store(v,
                reinterpret_cast<f32x4_t*>(&out[obase + (size_t)r * BATCH * NF]));
        }
    }
}

extern "C" void kernel_launch(void* const* d_in, const int* in_sizes, int n_in,
                              void* d_out, int out_size, void* d_ws, size_t ws_size,
                              hipStream_t stream) {
    const float* x = (const float*)d_in[0];
    const float* w = (const float*)d_in[1];
    float* out     = (float*)d_out;

    dim3 grid(NF / F_TILE, BATCH);   // (32, 32) = 1024 blocks, 4/CU resident
    dim3 block(256);
    lookahead_dwconv_kernel<<<grid, block, 0, stream>>>(x, w, out);
}